// Round 8
// baseline (94.783 us; speedup 1.0000x reference)
//
#include <hip/hip_runtime.h>
#include <hip/hip_bf16.h>
#include <stdint.h>

#define U_ROWS 4096
#define P_DIM  1024
#define TB     256     // block tile: 256x256
#define BK     64      // i8 k-bytes per window (2 k-steps of K=32)
#define NKT    (P_DIM / BK)   // 16 k-windows

typedef int i32x4  __attribute__((ext_vector_type(4)));
typedef int i32x16 __attribute__((ext_vector_type(16)));

// Row L2-normalize (eps-clamped), quantize q = clamp(round(512*x/||x||)).
// r6 lane-contiguous addressing kept (null but harmless; bit-identical
// output layout).  Global layout contract: within each 64-byte k-window,
// granule g (16 B) stored at slot g ^ ((row>>1)&3).
__global__ __launch_bounds__(256) void norm_i8_kernel(
    const float* __restrict__ in1, const float* __restrict__ in2,
    int8_t* __restrict__ out, float* __restrict__ loss_out) {
    const int w = threadIdx.x >> 6, lane = threadIdx.x & 63;
    const int row = blockIdx.x * 4 + w;
    const float* src = (row < U_ROWS) ? (in1 + (size_t)row * P_DIM)
                                      : (in2 + (size_t)(row - U_ROWS) * P_DIM);
    const float4* src4 = (const float4*)src;
    float4 v[4];
    float ss = 0.0f;
    #pragma unroll
    for (int j = 0; j < 4; ++j) {
        v[j] = src4[j * 64 + lane];      // dense 1 KB per instruction
        ss += v[j].x * v[j].x + v[j].y * v[j].y + v[j].z * v[j].z + v[j].w * v[j].w;
    }
    #pragma unroll
    for (int off = 32; off > 0; off >>= 1) ss += __shfl_xor(ss, off, 64);
    const float inv = 512.0f / fmaxf(sqrtf(ss), 1e-8f);

    const int key = (row >> 1) & 3;          // layout swizzle key
    int8_t* orow = out + (size_t)row * P_DIM;
    #pragma unroll
    for (int j = 0; j < 4; ++j) {
        int q0 = max(-127, min(127, (int)rintf(v[j].x * inv)));
        int q1 = max(-127, min(127, (int)rintf(v[j].y * inv)));
        int q2 = max(-127, min(127, (int)rintf(v[j].z * inv)));
        int q3 = max(-127, min(127, (int)rintf(v[j].w * inv)));
        const int d = (q0 & 255) | ((q1 & 255) << 8) | ((q2 & 255) << 16) | (q3 << 24);
        const int p0   = j * 256 + lane * 4;         // logical byte pos in row
        const int w0   = p0 >> 6;                    // 64-B k-window
        const int g    = (p0 >> 4) & 3;              // granule within window
        const int slot = g ^ key;                    // bank-spread swizzle
        *(int*)(orow + w0 * 64 + slot * 16 + (p0 & 15)) = d;
    }
    if (blockIdx.x == 0 && threadIdx.x == 0) *loss_out = 0.0f;
}

// C = N1*N2^T fused with sum((1-c)^2); int8 scaled by 512 -> acc = 2^18*cos.
// Block 256x256, 512 thr / 8 waves, wave tile 128x64.
//
// ROUND 7: FAITHFUL 8-phase template port (m201 anatomy), mapped to i8:
// 4 phases per K-window (= template's 4 phases per K-tile), phase =
// (slice s, mi-half mh):
//   phase body: { ds_reads(phase) ; stage half ; sched_barrier ;
//                 s_barrier(mid) ; s_waitcnt lgkmcnt(0) ; sched_barrier ;
//                 setprio(1) ; 4x mfma_i32_32x32x32_i8 ; setprio(0) ;
//                 sched_barrier ; s_barrier(end) }
// Reads: mh=0 phases load 2 A-frags + 2 B-frags; mh=1 phases load 2
// A-frags and REUSE B from registers (no redundancy; 12 ds_read/window).
// Stage: 4 gload_lds of window kt+2 split 2+2 into phases 1,3.
// vmcnt: counted ONCE per window -> vmcnt(4) folded before the window-
// opening barrier (= previous window's last end-barrier position); hits
// 0 only at kt=15.  3-buffer rotation; overwrite of buf[(kt+2)%3] ==
// buf[(kt-1)%3] is safe: its readers (window kt-1 phases) completed
// before window kt's opening barrier.
// Differences from failed probes: r1 had all reads before ONE cluster
// pair (no phase brackets); r2 moved reads across windows.  This is the
// template's exact per-phase interleave, which m196 A/B showed is the
// lever (coarse variants -7..-27%).
__global__ __launch_bounds__(512) void cosloss_gemm_i8(
    const int8_t* __restrict__ n1, const int8_t* __restrict__ n2,
    float* __restrict__ loss_out) {
    __shared__ __align__(16) uint8_t As[3][TB * BK];   // 3 x 16 KB
    __shared__ __align__(16) uint8_t Bs[3][TB * BK];   // 3 x 16 KB  (=96 KB)

    const int tid  = threadIdx.x;
    const int w    = tid >> 6;        // 0..7
    const int lane = tid & 63;

    // XCD swizzle (perf-only): id%8 -> XCD; each XCD works 2 cb panels.
    const int id  = blockIdx.x;         // 0..255
    const int xcd = id & 7;
    const int t   = id >> 3;            // 0..31
    const int cb  = xcd * 2 + (t & 1);  // 0..15
    const int rb  = t >> 1;             // 0..15

    const uint8_t* gA = (const uint8_t*)n1 + (size_t)rb * TB * P_DIM;
    const uint8_t* gB = (const uint8_t*)n2 + (size_t)cb * TB * P_DIM;

    // Staging: chunk = 16 rows x 64 B (1 KB); 32 chunks (16 A + 16 B), 4/wave.
    const int srow = lane >> 2;              // 0..15
    const int scol = (lane & 3) * 16;        // byte col within window
    const int c0   = w * 4;

    // Stage half: 2 of this wave's 4 chunks of window kt into buffer b.
    auto stage2 = [&](int kt, int b, int half) {
        #pragma unroll
        for (int cc = 2 * half; cc < 2 * half + 2; ++cc) {
            const int c = c0 + cc;
            const uint8_t* gsrc = (c < 16)
                ? gA + (size_t)(c * 16 + srow) * P_DIM + kt * BK + scol
                : gB + (size_t)((c - 16) * 16 + srow) * P_DIM + kt * BK + scol;
            uint8_t* sdst = (c < 16) ? As[b] + c * 1024 : Bs[b] + (c - 16) * 1024;
            __builtin_amdgcn_global_load_lds(
                (const __attribute__((address_space(1))) void*)gsrc,
                (__attribute__((address_space(3))) void*)sdst, 16, 0, 0);
        }
    };

    i32x16 acc[4][2];
    #pragma unroll
    for (int mi = 0; mi < 4; ++mi)
        #pragma unroll
        for (int ni = 0; ni < 2; ++ni)
            acc[mi][ni] = (i32x16){0,0,0,0,0,0,0,0,0,0,0,0,0,0,0,0};

    const int wr = (w & 1) * 128;     // wave row origin in 256
    const int wc = (w >> 1) * 64;     // wave col origin in 256
    const int lm = lane & 31;         // row within 32
    const int lh = lane >> 5;         // k-half selector

    // kt-invariant LDS fragment byte offsets (un-swizzle the granule):
    int aoff[4][2], boff[2][2];
    #pragma unroll
    for (int i = 0; i < 4; ++i) {
        const int m = wr + i * 32 + lm;
        #pragma unroll
        for (int s = 0; s < 2; ++s)
            aoff[i][s] = m * BK + (((2 * s + lh) ^ ((m >> 1) & 3)) * 16);
    }
    #pragma unroll
    for (int ni = 0; ni < 2; ++ni) {
        const int n = wc + ni * 32 + lm;
        #pragma unroll
        for (int s = 0; s < 2; ++s)
            boff[ni][s] = n * BK + (((2 * s + lh) ^ ((n >> 1) & 3)) * 16);
    }

    // Prologue: stage windows 0 and 1 (8 loads in flight).
    stage2(0, 0, 0); stage2(0, 0, 1);
    stage2(1, 1, 0); stage2(1, 1, 1);

    for (int kt = 0; kt < NKT; ++kt) {
        // Counted vmcnt ONCE per window, folded before the opening barrier.
        // Outstanding here: 4 loads of DMA(kt+1) (+ own DMA(kt) to drain).
        if (kt < NKT - 1) {
            asm volatile("s_waitcnt vmcnt(4)" ::: "memory");
        } else {
            asm volatile("s_waitcnt vmcnt(0)" ::: "memory");
        }
        __builtin_amdgcn_s_barrier();        // publishes buf[kt]; separates
                                             // prev window's reads from stage
        __builtin_amdgcn_sched_barrier(0);

        const uint8_t* Ab = As[kt % 3];
        const uint8_t* Bb = Bs[kt % 3];
        const int    pb   = (kt + 2) % 3;    // prefetch dest buffer
        const bool   pf   = (kt + 2) < NKT;

        i32x4 a0, a1, b0, b1;                // phase-local A / window B frags

        // ================= Phase 1: s=0, mh=0 =================
        a0 = *(const i32x4*)(Ab + aoff[0][0]);
        a1 = *(const i32x4*)(Ab + aoff[1][0]);
        b0 = *(const i32x4*)(Bb + boff[0][0]);
        b1 = *(const i32x4*)(Bb + boff[1][0]);
        if (pf) stage2(kt + 2, pb, 0);
        __builtin_amdgcn_sched_barrier(0);
        __builtin_amdgcn_s_barrier();                        // mid
        asm volatile("s_waitcnt lgkmcnt(0)" ::: "memory");
        __builtin_amdgcn_sched_barrier(0);
        __builtin_amdgcn_s_setprio(1);
        acc[0][0] = __builtin_amdgcn_mfma_i32_32x32x32_i8(a0, b0, acc[0][0], 0, 0, 0);
        acc[0][1] = __builtin_amdgcn_mfma_i32_32x32x32_i8(a0, b1, acc[0][1], 0, 0, 0);
        acc[1][0] = __builtin_amdgcn_mfma_i32_32x32x32_i8(a1, b0, acc[1][0], 0, 0, 0);
        acc[1][1] = __builtin_amdgcn_mfma_i32_32x32x32_i8(a1, b1, acc[1][1], 0, 0, 0);
        __builtin_amdgcn_s_setprio(0);
        __builtin_amdgcn_sched_barrier(0);
        __builtin_amdgcn_s_barrier();                        // end

        // ================= Phase 2: s=0, mh=1 =================
        a0 = *(const i32x4*)(Ab + aoff[2][0]);
        a1 = *(const i32x4*)(Ab + aoff[3][0]);
        __builtin_amdgcn_sched_barrier(0);
        __builtin_amdgcn_s_barrier();                        // mid
        asm volatile("s_waitcnt lgkmcnt(0)" ::: "memory");
        __builtin_amdgcn_sched_barrier(0);
        __builtin_amdgcn_s_setprio(1);
        acc[2][0] = __builtin_amdgcn_mfma_i32_32x32x32_i8(a0, b0, acc[2][0], 0, 0, 0);
        acc[2][1] = __builtin_amdgcn_mfma_i32_32x32x32_i8(a0, b1, acc[2][1], 0, 0, 0);
        acc[3][0] = __builtin_amdgcn_mfma_i32_32x32x32_i8(a1, b0, acc[3][0], 0, 0, 0);
        acc[3][1] = __builtin_amdgcn_mfma_i32_32x32x32_i8(a1, b1, acc[3][1], 0, 0, 0);
        __builtin_amdgcn_s_setprio(0);
        __builtin_amdgcn_sched_barrier(0);
        __builtin_amdgcn_s_barrier();                        // end

        // ================= Phase 3: s=1, mh=0 =================
        a0 = *(const i32x4*)(Ab + aoff[0][1]);
        a1 = *(const i32x4*)(Ab + aoff[1][1]);
        b0 = *(const i32x4*)(Bb + boff[0][1]);
        b1 = *(const i32x4*)(Bb + boff[1][1]);
        if (pf) stage2(kt + 2, pb, 1);
        __builtin_amdgcn_sched_barrier(0);
        __builtin_amdgcn_s_barrier();                        // mid
        asm volatile("s_waitcnt lgkmcnt(0)" ::: "memory");
        __builtin_amdgcn_sched_barrier(0);
        __builtin_amdgcn_s_setprio(1);
        acc[0][0] = __builtin_amdgcn_mfma_i32_32x32x32_i8(a0, b0, acc[0][0], 0, 0, 0);
        acc[0][1] = __builtin_amdgcn_mfma_i32_32x32x32_i8(a0, b1, acc[0][1], 0, 0, 0);
        acc[1][0] = __builtin_amdgcn_mfma_i32_32x32x32_i8(a1, b0, acc[1][0], 0, 0, 0);
        acc[1][1] = __builtin_amdgcn_mfma_i32_32x32x32_i8(a1, b1, acc[1][1], 0, 0, 0);
        __builtin_amdgcn_s_setprio(0);
        __builtin_amdgcn_sched_barrier(0);
        __builtin_amdgcn_s_barrier();                        // end

        // ================= Phase 4: s=1, mh=1 =================
        a0 = *(const i32x4*)(Ab + aoff[2][1]);
        a1 = *(const i32x4*)(Ab + aoff[3][1]);
        __builtin_amdgcn_sched_barrier(0);
        __builtin_amdgcn_s_barrier();                        // mid
        asm volatile("s_waitcnt lgkmcnt(0)" ::: "memory");
        __builtin_amdgcn_sched_barrier(0);
        __builtin_amdgcn_s_setprio(1);
        acc[2][0] = __builtin_amdgcn_mfma_i32_32x32x32_i8(a0, b0, acc[2][0], 0, 0, 0);
        acc[2][1] = __builtin_amdgcn_mfma_i32_32x32x32_i8(a0, b1, acc[2][1], 0, 0, 0);
        acc[3][0] = __builtin_amdgcn_mfma_i32_32x32x32_i8(a1, b0, acc[3][0], 0, 0, 0);
        acc[3][1] = __builtin_amdgcn_mfma_i32_32x32x32_i8(a1, b1, acc[3][1], 0, 0, 0);
        __builtin_amdgcn_s_setprio(0);
        __builtin_amdgcn_sched_barrier(0);
        // end-barrier of phase 4 == next window's opening barrier
        // (vmcnt folded before it at loop top).
    }

    // Epilogue: acc = 2^18 * cos -> sum (1 - acc*2^-18)^2.
    float local = 0.0f;
    #pragma unroll
    for (int mi = 0; mi < 4; ++mi)
        #pragma unroll
        for (int ni = 0; ni < 2; ++ni)
            #pragma unroll
            for (int r = 0; r < 16; ++r) {
                const float dd = 1.0f - (float)acc[mi][ni][r] * (1.0f / 262144.0f);
                local += dd * dd;
            }
    #pragma unroll
    for (int off = 32; off > 0; off >>= 1) local += __shfl_down(local, off, 64);

    __syncthreads();                       // done with LDS tiles
    float* redf = (float*)As;              // reuse LDS for reduction
    if (lane == 0) redf[w] = local;
    __syncthreads();
    if (tid == 0) {
        float tsum = 0.0f;
        #pragma unroll
        for (int i = 0; i < 8; ++i) tsum += redf[i];
        atomicAdd(loss_out, tsum);
    }
}

extern "C" void kernel_launch(void* const* d_in, const int* in_sizes, int n_in,
                              void* d_out, int out_size, void* d_ws, size_t ws_size,
                              hipStream_t stream) {
    const float* in1 = (const float*)d_in[0];
    const float* in2 = (const float*)d_in[1];
    float* out = (float*)d_out;
    int8_t* nrm = (int8_t*)d_ws;                   // 8192x1024 i8 = 8 MB

    norm_i8_kernel<<<(U_ROWS * 2) / 4, 256, 0, stream>>>(in1, in2, nrm, out);

    cosloss_gemm_i8<<<(U_ROWS / TB) * (U_ROWS / TB), 512, 0, stream>>>(
        nrm, nrm + (size_t)U_ROWS * P_DIM, out);
}